// Round 5
// baseline (121.054 us; speedup 1.0000x reference)
//
#include <hip/hip_runtime.h>
#include <hip/hip_bf16.h>

#define B_N 2048
#define D_V 8
#define F_D 256
#define TILE 128
#define BC 64
#define LSTR 266   // 266 shorts = 133 dwords == 5 (mod 32): read bank window
                   // (5*li + 4*q) mod 32 -> 1-3 lanes/window (mostly 2-way = free).
                   // Old 264 (==4 mod 32) was a measured 8-way conflict (557K, R1).

// sqrt(2*log2(e)) : zn scaled by this => MFMA acc = 2*log2(e)*dot => exp(2*dot) = exp2(acc)
#define SCALE_F 1.69864364f

#if defined(__has_builtin)
#  if __has_builtin(__builtin_amdgcn_exp2f)
#    define EXP2F(x) __builtin_amdgcn_exp2f(x)
#  else
#    define EXP2F(x) exp2f(x)
#  endif
#else
#  define EXP2F(x) exp2f(x)
#endif

typedef __attribute__((ext_vector_type(8))) short short8;
typedef __attribute__((ext_vector_type(4))) float floatx4;

__device__ inline unsigned short f2bf(float f) {
    __hip_bfloat16 h = __float2bfloat16(f);
    return *reinterpret_cast<unsigned short*>(&h);
}

__device__ inline float wave_reduce_sum(float v) {
    #pragma unroll
    for (int off = 1; off < 64; off <<= 1)
        v += __shfl_xor(v, off, 64);
    return v;
}

// ---------------------------------------------------------------------------
// Kernel 1: normalize each (b,d) row of 256 floats; write bf16 zn (pre-scaled
// by SCALE_F) in [d][b][f] layout. One wave per row (16384 waves -> fully
// latency-hidden). Also zero-inits ns8[8][2048].
// ---------------------------------------------------------------------------
__global__ void norm_kernel(const float* __restrict__ z,
                            unsigned short* __restrict__ zn,
                            float* __restrict__ ns8) {
    int gid = blockIdx.x * blockDim.x + threadIdx.x;
    if (gid < D_V * B_N) ns8[gid] = 0.0f;
    int wave = gid >> 6;  // row = b*8+d
    int lane = threadIdx.x & 63;
    const float4* zp = (const float4*)(z + (size_t)wave * F_D);
    float4 v = zp[lane];
    float ss = v.x * v.x + v.y * v.y + v.z * v.z + v.w * v.w;
    ss = wave_reduce_sum(ss);
    float inv = SCALE_F / fmaxf(sqrtf(ss), 1e-12f);
    int b = wave >> 3, d = wave & 7;
    unsigned short* op = zn + (size_t)d * (B_N * F_D) + (size_t)b * F_D + lane * 4;
    ushort4 o;
    o.x = f2bf(v.x * inv);
    o.y = f2bf(v.y * inv);
    o.z = f2bf(v.z * inv);
    o.w = f2bf(v.w * inv);
    *(ushort4*)op = o;
}

// ---------------------------------------------------------------------------
// Kernel 2: pos[b] = sum_{d!=e} exp(2*dot(zn[b,d], zn[b,e]))
// One wave handles 2 samples: 16 rows = [s0 views 0..7 | s1 views 0..7].
// acc already = 2*log2e*dot -> single v_exp.
// ---------------------------------------------------------------------------
__global__ void pos_kernel(const unsigned short* __restrict__ zn,
                           float* __restrict__ pos) {
    int gw = (blockIdx.x * blockDim.x + threadIdx.x) >> 6;
    int lane = threadIdx.x & 63;
    int q = lane >> 4, li = lane & 15;
    int s0 = gw * 2;
    int b = s0 + (li >> 3), d = li & 7;
    const unsigned short* rowp = zn + (size_t)d * (B_N * F_D) + (size_t)b * F_D;
    short8 a[8];
    #pragma unroll
    for (int kk = 0; kk < 8; kk++)
        a[kk] = *(const short8*)(rowp + kk * 32 + q * 8);
    floatx4 acc = {0.f, 0.f, 0.f, 0.f};
    #pragma unroll
    for (int kk = 0; kk < 8; kk++)
        acc = __builtin_amdgcn_mfma_f32_16x16x32_bf16(a[kk], a[kk], acc, 0, 0, 0);
    float p0 = 0.f, p1 = 0.f;
    #pragma unroll
    for (int r = 0; r < 4; r++) {
        int row = q * 4 + r, col = li;
        bool same_sample = (row >> 3) == (col >> 3);
        if (same_sample && row != col) {
            float e = EXP2F(acc[r]);
            if (row < 8) p0 += e; else p1 += e;
        }
    }
    p0 = wave_reduce_sum(p0);
    p1 = wave_reduce_sum(p1);
    if (lane == 0) { pos[s0] = p0; pos[s0 + 1] = p1; }
}

// ---------------------------------------------------------------------------
// Kernel 3 (symmetric-halved): per view d, for upper-triangle 128x128 tiles
// (i<=j) of S = exp(2 * Z Z^T): row-sums -> ns8[d][i*128+..]; for off-diag
// tiles also col-sums -> ns8[d][j*128+..] (covers the mirrored tile).
// R0-proven structure: block = 128 threads (2 waves); each wave owns 64
// A-rows (4 MFMA row-sets, K=256 resident); B staged in LDS 64 cols at a
// time. Round-4 local fixes on top: (a) LSTR 266 kills the measured 8-way
// ds_read conflict, (b) 1-D grid d=bid&7 restores XCD-L2 pinning (FETCH
// 10.4 vs 38.7 MB measured), (c) exp2-prescaled epilogue, diag branch
// uniform (16/136 blocks only).
// ---------------------------------------------------------------------------
__global__ __launch_bounds__(128, 2)
void neg_kernel(const unsigned short* __restrict__ zn,
                float* __restrict__ ns8) {
    __shared__ __align__(16) unsigned short Bs[BC * LSTR];  // ~34 KB
    __shared__ float csred[2][TILE];
    const int bid = blockIdx.x;
    const int d = bid & 7;            // view == XCD (perf heuristic only)
    int trem = bid >> 3;              // 0..135 -> (i,j), i<=j
    int i = 0;
    while (trem >= 16 - i) { trem -= 16 - i; ++i; }
    const int j = i + trem;
    const bool diag = (i == j);
    const unsigned short* Z = zn + (size_t)d * (B_N * F_D);
    int tid = threadIdx.x, w = tid >> 6, lane = tid & 63;
    int q = lane >> 4, li = lane & 15;
    int r0 = i * TILE + w * 64;       // this wave's 64 A-rows

    short8 a[4][8];
    #pragma unroll
    for (int s = 0; s < 4; s++)
        #pragma unroll
        for (int kk = 0; kk < 8; kk++)
            a[s][kk] = *(const short8*)(Z + (size_t)(r0 + s * 16 + li) * F_D + kk * 32 + q * 8);

    float rs[4][4];
    #pragma unroll
    for (int s = 0; s < 4; s++)
        #pragma unroll
        for (int r = 0; r < 4; r++) rs[s][r] = 0.f;
    float cacc[2] = {0.f, 0.f};

    #pragma unroll
    for (int stage = 0; stage < 2; ++stage) {
        int c0 = j * TILE + stage * BC;
        __syncthreads();
        // stage 64 rows x 256 shorts: 2048 16B-chunks, 16 per thread (coalesced)
        #pragma unroll
        for (int it = 0; it < 16; ++it) {
            int idx = it * 128 + tid;
            int row = idx >> 5, kc = idx & 31;
            *(short8*)(&Bs[row * LSTR + kc * 8]) =
                *(const short8*)(Z + (size_t)(c0 + row) * F_D + kc * 8);
        }
        __syncthreads();
        #pragma unroll
        for (int ct = 0; ct < 4; ++ct) {
            short8 bf[8];
            #pragma unroll
            for (int kk = 0; kk < 8; kk++)
                bf[kk] = *(const short8*)(&Bs[(ct * 16 + li) * LSTR + kk * 32 + q * 8]);
            floatx4 acc[4];
            #pragma unroll
            for (int s = 0; s < 4; s++) acc[s] = (floatx4){0.f, 0.f, 0.f, 0.f};
            #pragma unroll
            for (int kk = 0; kk < 8; kk++)
                #pragma unroll
                for (int s = 0; s < 4; s++)
                    acc[s] = __builtin_amdgcn_mfma_f32_16x16x32_bf16(a[s][kk], bf[kk], acc[s], 0, 0, 0);
            // C/D layout: col = li, row(within set) = q*4 + r
            int gcol = c0 + ct * 16 + li;
            float csum = 0.f;
            #pragma unroll
            for (int s = 0; s < 4; s++) {
                #pragma unroll
                for (int r = 0; r < 4; r++) {
                    float e = EXP2F(acc[s][r]);        // exp(2*dot), 1 trans op
                    if (diag) {                        // uniform: 16/136 blocks
                        int grow = r0 + s * 16 + q * 4 + r;
                        if (grow == gcol) e = 0.f;
                    }
                    rs[s][r] += e;
                    csum += e;
                }
            }
            // colsum over this wave's 64 rows: reduce across q-groups
            csum += __shfl_xor(csum, 16, 64);
            csum += __shfl_xor(csum, 32, 64);
            // holder: lane (ct*16+li) keeps col (stage*64 + ct*16 + li)
            if (q == ct) cacc[stage] += csum;
        }
    }

    // row sums: reduce across the 16 column-lanes
    #pragma unroll
    for (int off = 1; off < 16; off <<= 1)
        #pragma unroll
        for (int s = 0; s < 4; s++)
            #pragma unroll
            for (int r = 0; r < 4; r++)
                rs[s][r] += __shfl_xor(rs[s][r], off, 64);
    if (li == 0) {
        #pragma unroll
        for (int s = 0; s < 4; s++)
            #pragma unroll
            for (int r = 0; r < 4; r++)
                atomicAdd(&ns8[d * B_N + r0 + s * 16 + q * 4 + r], rs[s][r]);
    }

    // col sums: combine the 2 waves in LDS, then one atomic per column
    csred[w][lane] = cacc[0];
    csred[w][64 + lane] = cacc[1];
    __syncthreads();
    if (!diag && tid < TILE) {
        float v = csred[0][tid] + csred[1][tid];
        atomicAdd(&ns8[d * B_N + j * TILE + tid], v);
    }
}

// ---------------------------------------------------------------------------
// Kernel 4: neg[b] = sum_d ns8[d][b] / (B-1); logits = pos/(pos+neg);
// loss = max + log(sum exp(l-max)) - mean(l)
// ---------------------------------------------------------------------------
__global__ void final_kernel(const float* __restrict__ pos,
                             const float* __restrict__ ns8,
                             float* __restrict__ out) {
    __shared__ float red[256];
    int t = threadIdx.x;
    float vals[8];
    float lmax = -1e30f;
    #pragma unroll
    for (int i = 0; i < 8; i++) {
        int idx = t * 8 + i;
        float nsum = 0.f;
        #pragma unroll
        for (int d = 0; d < D_V; d++) nsum += ns8[d * B_N + idx];
        float p = pos[idx];
        float n = nsum * (1.0f / (float)(B_N - 1));
        float l = p / (p + n);
        vals[i] = l;
        lmax = fmaxf(lmax, l);
    }
    red[t] = lmax; __syncthreads();
    for (int s = 128; s > 0; s >>= 1) {
        if (t < s) red[t] = fmaxf(red[t], red[t + s]);
        __syncthreads();
    }
    float m = red[0]; __syncthreads();
    float se = 0.f, sl = 0.f;
    #pragma unroll
    for (int i = 0; i < 8; i++) { se += expf(vals[i] - m); sl += vals[i]; }
    red[t] = se; __syncthreads();
    for (int s = 128; s > 0; s >>= 1) {
        if (t < s) red[t] += red[t + s];
        __syncthreads();
    }
    float S = red[0]; __syncthreads();
    red[t] = sl; __syncthreads();
    for (int s = 128; s > 0; s >>= 1) {
        if (t < s) red[t] += red[t + s];
        __syncthreads();
    }
    if (t == 0) out[0] = m + logf(S) - red[0] / (float)B_N;
}

extern "C" void kernel_launch(void* const* d_in, const int* in_sizes, int n_in,
                              void* d_out, int out_size, void* d_ws, size_t ws_size,
                              hipStream_t stream) {
    const float* z = (const float*)d_in[0];
    float* out = (float*)d_out;
    unsigned short* zn = (unsigned short*)d_ws;                        // 8 MB bf16 (pre-scaled)
    float* ns8 = (float*)((char*)d_ws + (size_t)D_V * B_N * F_D * 2);  // 64 KB
    float* pos = ns8 + D_V * B_N;                                      // 8 KB

    norm_kernel<<<dim3(4096), 256, 0, stream>>>(z, zn, ns8);
    pos_kernel<<<dim3(256), 256, 0, stream>>>(zn, pos);
    neg_kernel<<<dim3(136 * 8), 128, 0, stream>>>(zn, ns8);
    final_kernel<<<1, 256, 0, stream>>>(pos, ns8, out);
}

// Round 6
// 95.088 us; speedup vs baseline: 1.2731x; 1.2731x over previous
//
#include <hip/hip_runtime.h>
#include <hip/hip_bf16.h>

#define B_N 2048
#define D_V 8
#define F_D 256
#define TILE 128
#define BC 64
#define LSTR 264   // 132 dwords == 4 (mod 32). For ds_*_b128, waves are serviced in
                   // 8-lane phases; lane li's 4-dword window starts at bank 4*li+c ->
                   // windows {0,4,...,28} tile all 32 banks: conflict-free.
                   // (R1's 557K count at 264 = benign 2-way sub-phase aliasing, free
                   // per m136. 266 (==5) gave REAL overlap: 2.79M measured, R5.)

// sqrt(2*log2(e)) : zn scaled by this => MFMA acc = 2*log2(e)*dot => exp(2*dot) = exp2(acc)
#define SCALE_F 1.69864364f

#if defined(__has_builtin)
#  if __has_builtin(__builtin_amdgcn_exp2f)
#    define EXP2F(x) __builtin_amdgcn_exp2f(x)
#  else
#    define EXP2F(x) exp2f(x)
#  endif
#else
#  define EXP2F(x) exp2f(x)
#endif

typedef __attribute__((ext_vector_type(8))) short short8;
typedef __attribute__((ext_vector_type(4))) float floatx4;

__device__ inline unsigned short f2bf(float f) {
    __hip_bfloat16 h = __float2bfloat16(f);
    return *reinterpret_cast<unsigned short*>(&h);
}

__device__ inline float wave_reduce_sum(float v) {
    #pragma unroll
    for (int off = 1; off < 64; off <<= 1)
        v += __shfl_xor(v, off, 64);
    return v;
}

// ---------------------------------------------------------------------------
// Kernel 1: normalize each (b,d) row of 256 floats; write bf16 zn (pre-scaled
// by SCALE_F) in [d][b][f] layout. One wave per row. Zero-inits ns8.
// ---------------------------------------------------------------------------
__global__ void norm_kernel(const float* __restrict__ z,
                            unsigned short* __restrict__ zn,
                            float* __restrict__ ns8) {
    int gid = blockIdx.x * blockDim.x + threadIdx.x;
    if (gid < D_V * B_N) ns8[gid] = 0.0f;
    int wave = gid >> 6;  // row = b*8+d
    int lane = threadIdx.x & 63;
    const float4* zp = (const float4*)(z + (size_t)wave * F_D);
    float4 v = zp[lane];
    float ss = v.x * v.x + v.y * v.y + v.z * v.z + v.w * v.w;
    ss = wave_reduce_sum(ss);
    float inv = SCALE_F / fmaxf(sqrtf(ss), 1e-12f);
    int b = wave >> 3, d = wave & 7;
    unsigned short* op = zn + (size_t)d * (B_N * F_D) + (size_t)b * F_D + lane * 4;
    ushort4 o;
    o.x = f2bf(v.x * inv);
    o.y = f2bf(v.y * inv);
    o.z = f2bf(v.z * inv);
    o.w = f2bf(v.w * inv);
    *(ushort4*)op = o;
}

// ---------------------------------------------------------------------------
// Kernel 2: pos[b] = sum_{d!=e} exp(2*dot(zn[b,d], zn[b,e]))
// One wave handles 2 samples; acc already = 2*log2e*dot -> single v_exp.
// ---------------------------------------------------------------------------
__global__ void pos_kernel(const unsigned short* __restrict__ zn,
                           float* __restrict__ pos) {
    int gw = (blockIdx.x * blockDim.x + threadIdx.x) >> 6;
    int lane = threadIdx.x & 63;
    int q = lane >> 4, li = lane & 15;
    int s0 = gw * 2;
    int b = s0 + (li >> 3), d = li & 7;
    const unsigned short* rowp = zn + (size_t)d * (B_N * F_D) + (size_t)b * F_D;
    short8 a[8];
    #pragma unroll
    for (int kk = 0; kk < 8; kk++)
        a[kk] = *(const short8*)(rowp + kk * 32 + q * 8);
    floatx4 acc = {0.f, 0.f, 0.f, 0.f};
    #pragma unroll
    for (int kk = 0; kk < 8; kk++)
        acc = __builtin_amdgcn_mfma_f32_16x16x32_bf16(a[kk], a[kk], acc, 0, 0, 0);
    float p0 = 0.f, p1 = 0.f;
    #pragma unroll
    for (int r = 0; r < 4; r++) {
        int row = q * 4 + r, col = li;
        bool same_sample = (row >> 3) == (col >> 3);
        if (same_sample && row != col) {
            float e = EXP2F(acc[r]);
            if (row < 8) p0 += e; else p1 += e;
        }
    }
    p0 = wave_reduce_sum(p0);
    p1 = wave_reduce_sum(p1);
    if (lane == 0) { pos[s0] = p0; pos[s0 + 1] = p1; }
}

// ---------------------------------------------------------------------------
// Kernel 3 (symmetric-halved): per view d, upper-triangle 128x128 tiles of
// S = exp(2 * Z Z^T): row-sums -> ns8[d][i*128+..]; off-diag tiles also
// col-sums -> ns8[d][j*128+..] (mirrored tile).
// R2's SPILL-FREE structure (measured VGPR=76, WRITE 2.4 MB): 256 threads
// (4 waves), each wave owns 32 A-rows (a[2][8] = 64 VGPR resident); B staged
// in LDS 64 cols at a time; per-kk bf load.
// Fixes vs R2 (both defects measured): LSTR 258->264 (kills REAL 4-way read
// conflict, 1.67M); 2-D grid -> 1-D d=bid&7 (XCD-L2 pinning: FETCH 10.4 vs
// 38.7 MB, R1 vs R2).
// ---------------------------------------------------------------------------
__global__ __launch_bounds__(256)
void neg_kernel(const unsigned short* __restrict__ zn,
                float* __restrict__ ns8) {
    __shared__ __align__(16) unsigned short Bs[BC * LSTR];  // 33 KB -> 4 blocks/CU
    const int bid = blockIdx.x;
    const int d = bid & 7;            // view == XCD (perf heuristic only)
    int trem = bid >> 3;              // 0..135 -> (i,j), i<=j
    int i = 0;
    while (trem >= 16 - i) { trem -= 16 - i; ++i; }
    const int j = i + trem;
    const bool diag = (i == j);
    const unsigned short* Z = zn + (size_t)d * (B_N * F_D);
    int tid = threadIdx.x, w = tid >> 6, lane = tid & 63;
    int q = lane >> 4, li = lane & 15;
    int r0 = i * TILE + w * 32;       // this wave's 32 A-rows

    short8 a[2][8];                   // 64 VGPRs, resident whole kernel
    #pragma unroll
    for (int s = 0; s < 2; s++)
        #pragma unroll
        for (int kk = 0; kk < 8; kk++)
            a[s][kk] = *(const short8*)(Z + (size_t)(r0 + s * 16 + li) * F_D + kk * 32 + q * 8);

    float rs[2][4];
    #pragma unroll
    for (int s = 0; s < 2; s++)
        #pragma unroll
        for (int r = 0; r < 4; r++) rs[s][r] = 0.f;
    float cs[8];

    #pragma unroll
    for (int stage = 0; stage < 2; ++stage) {
        int c0 = j * TILE + stage * BC;
        __syncthreads();
        // stage 64 rows x 256 shorts: 2048 16B-chunks, 8 per thread (coalesced;
        // write phases also bank-tile: banks 4*kc + 132*row)
        #pragma unroll
        for (int it = 0; it < 8; ++it) {
            int idx = it * 256 + tid;
            int row = idx >> 5, kc = idx & 31;
            *(short8*)(&Bs[row * LSTR + kc * 8]) =
                *(const short8*)(Z + (size_t)(c0 + row) * F_D + kc * 8);
        }
        __syncthreads();
        #pragma unroll
        for (int ct = 0; ct < 4; ++ct) {
            const unsigned short* bp = &Bs[(ct * 16 + li) * LSTR + q * 8];
            floatx4 acc[2];
            acc[0] = (floatx4){0.f, 0.f, 0.f, 0.f};
            acc[1] = (floatx4){0.f, 0.f, 0.f, 0.f};
            // per-kk bf load keeps live B-frags small (no spill: R2 VGPR=76)
            #pragma unroll
            for (int kk = 0; kk < 8; kk++) {
                short8 bf = *(const short8*)(bp + kk * 32);
                acc[0] = __builtin_amdgcn_mfma_f32_16x16x32_bf16(a[0][kk], bf, acc[0], 0, 0, 0);
                acc[1] = __builtin_amdgcn_mfma_f32_16x16x32_bf16(a[1][kk], bf, acc[1], 0, 0, 0);
            }
            // C/D layout: col = li, row(within set) = q*4 + r
            int gcol = c0 + ct * 16 + li;
            float csum = 0.f;
            #pragma unroll
            for (int s = 0; s < 2; s++) {
                #pragma unroll
                for (int r = 0; r < 4; r++) {
                    float e = EXP2F(acc[s][r]);        // exp(2*dot), 1 trans op
                    if (diag) {                        // uniform: 16/136 blocks
                        int grow = r0 + s * 16 + q * 4 + r;
                        if (grow == gcol) e = 0.f;
                    }
                    rs[s][r] += e;
                    csum += e;
                }
            }
            cs[stage * 4 + ct] = csum;  // static index (loops unrolled)
        }
    }

    // row sums: reduce across the 16 column-lanes; lanes li<8 each own one
    // (s,r) value and issue one atomic
    #pragma unroll
    for (int off = 1; off < 16; off <<= 1)
        #pragma unroll
        for (int s = 0; s < 2; s++)
            #pragma unroll
            for (int r = 0; r < 4; r++)
                rs[s][r] += __shfl_xor(rs[s][r], off, 64);
    {
        float rv = 0.f;
        #pragma unroll
        for (int s = 0; s < 2; s++)
            #pragma unroll
            for (int r = 0; r < 4; r++)
                if (li == s * 4 + r) rv = rs[s][r];
        if (li < 8)
            atomicAdd(&ns8[d * B_N + r0 + (li >> 2) * 16 + q * 4 + (li & 3)], rv);
    }

    // col sums (mirrored tile coverage): cross-q reduce; each wave atomics its
    // own 32-row contribution (4 waves -> 4 atomics/column, negligible)
    if (!diag) {
        #pragma unroll
        for (int c = 0; c < 8; c++) {
            cs[c] += __shfl_xor(cs[c], 16, 64);
            cs[c] += __shfl_xor(cs[c], 32, 64);
        }
        float v0 = 0.f, v1 = 0.f;
        #pragma unroll
        for (int c = 0; c < 4; c++)
            if (q == c) { v0 = cs[c]; v1 = cs[c + 4]; }
        atomicAdd(&ns8[d * B_N + j * TILE + q * 16 + li], v0);
        atomicAdd(&ns8[d * B_N + j * TILE + 64 + q * 16 + li], v1);
    }
}

// ---------------------------------------------------------------------------
// Kernel 4: neg[b] = sum_d ns8[d][b] / (B-1); logits = pos/(pos+neg);
// loss = max + log(sum exp(l-max)) - mean(l)
// ---------------------------------------------------------------------------
__global__ void final_kernel(const float* __restrict__ pos,
                             const float* __restrict__ ns8,
                             float* __restrict__ out) {
    __shared__ float red[256];
    int t = threadIdx.x;
    float vals[8];
    float lmax = -1e30f;
    #pragma unroll
    for (int i = 0; i < 8; i++) {
        int idx = t * 8 + i;
        float nsum = 0.f;
        #pragma unroll
        for (int d = 0; d < D_V; d++) nsum += ns8[d * B_N + idx];
        float p = pos[idx];
        float n = nsum * (1.0f / (float)(B_N - 1));
        float l = p / (p + n);
        vals[i] = l;
        lmax = fmaxf(lmax, l);
    }
    red[t] = lmax; __syncthreads();
    for (int s = 128; s > 0; s >>= 1) {
        if (t < s) red[t] = fmaxf(red[t], red[t + s]);
        __syncthreads();
    }
    float m = red[0]; __syncthreads();
    float se = 0.f, sl = 0.f;
    #pragma unroll
    for (int i = 0; i < 8; i++) { se += expf(vals[i] - m); sl += vals[i]; }
    red[t] = se; __syncthreads();
    for (int s = 128; s > 0; s >>= 1) {
        if (t < s) red[t] += red[t + s];
        __syncthreads();
    }
    float S = red[0]; __syncthreads();
    red[t] = sl; __syncthreads();
    for (int s = 128; s > 0; s >>= 1) {
        if (t < s) red[t] += red[t + s];
        __syncthreads();
    }
    if (t == 0) out[0] = m + logf(S) - red[0] / (float)B_N;
}

extern "C" void kernel_launch(void* const* d_in, const int* in_sizes, int n_in,
                              void* d_out, int out_size, void* d_ws, size_t ws_size,
                              hipStream_t stream) {
    const float* z = (const float*)d_in[0];
    float* out = (float*)d_out;
    unsigned short* zn = (unsigned short*)d_ws;                        // 8 MB bf16 (pre-scaled)
    float* ns8 = (float*)((char*)d_ws + (size_t)D_V * B_N * F_D * 2);  // 64 KB
    float* pos = ns8 + D_V * B_N;                                      // 8 KB

    norm_kernel<<<dim3(4096), 256, 0, stream>>>(z, zn, ns8);
    pos_kernel<<<dim3(256), 256, 0, stream>>>(zn, pos);
    neg_kernel<<<dim3(136 * 8), 256, 0, stream>>>(zn, ns8);
    final_kernel<<<1, 256, 0, stream>>>(pos, ns8, out);
}

// Round 7
// 86.268 us; speedup vs baseline: 1.4032x; 1.1022x over previous
//
#include <hip/hip_runtime.h>
#include <hip/hip_bf16.h>

#define B_N 2048
#define D_V 8
#define F_D 256
#define TILE 128
#define BC 64
#define LSTR 264   // 132 dwords == 4 (mod 32). For ds_*_b128, waves are serviced in
                   // 8-lane phases; lane li's 4-dword window starts at bank 4*li+c ->
                   // windows {0,4,...,28} tile all 32 banks: conflict-free.
                   // (557K count at 264 = benign 2-way sub-phase aliasing, free per
                   // m136. 258 (==1) was a real 4-way: 1.67M, R2. 266 (==5): 2.79M, R5.)

// sqrt(2*log2(e)) : zn scaled by this => MFMA acc = 2*log2(e)*dot => exp(2*dot) = exp2(acc)
#define SCALE_F 1.69864364f

#if defined(__has_builtin)
#  if __has_builtin(__builtin_amdgcn_exp2f)
#    define EXP2F(x) __builtin_amdgcn_exp2f(x)
#  else
#    define EXP2F(x) exp2f(x)
#  endif
#else
#  define EXP2F(x) exp2f(x)
#endif

typedef __attribute__((ext_vector_type(8))) short short8;
typedef __attribute__((ext_vector_type(4))) float floatx4;

__device__ inline unsigned short f2bf(float f) {
    __hip_bfloat16 h = __float2bfloat16(f);
    return *reinterpret_cast<unsigned short*>(&h);
}

__device__ inline float wave_reduce_sum(float v) {
    #pragma unroll
    for (int off = 1; off < 64; off <<= 1)
        v += __shfl_xor(v, off, 64);
    return v;
}

// ---------------------------------------------------------------------------
// Kernel 1: fused normalize + pos (R1-verified structure). Block = 256
// threads (4 waves) handles 4 samples (32 rows). Each wave normalizes its
// sample's 8 rows (writing scaled bf16 zn to global [d][b][f] AND to LDS),
// then waves 0/1 compute pos for 2 samples each via MFMA straight from LDS
// (kills pos's 8 MB global re-read + one launch boundary).
// Also zero-inits ns8[8][2048].
// ---------------------------------------------------------------------------
__global__ __launch_bounds__(256)
void np_kernel(const float* __restrict__ z, unsigned short* __restrict__ zn,
               float* __restrict__ ns8, float* __restrict__ pos) {
    __shared__ __align__(16) unsigned short Zs[32 * LSTR];  // 16.5 KB
    int tid = threadIdx.x;
    int gid = blockIdx.x * 256 + tid;
    if (gid < D_V * B_N) ns8[gid] = 0.0f;

    int w = tid >> 6, lane = tid & 63;
    int b = blockIdx.x * 4 + w;  // this wave's sample
    #pragma unroll
    for (int k = 0; k < 8; k++) {
        const float4 v = ((const float4*)(z + ((size_t)b * 8 + k) * F_D))[lane];
        float ss = v.x * v.x + v.y * v.y + v.z * v.z + v.w * v.w;
        ss = wave_reduce_sum(ss);
        float inv = SCALE_F / fmaxf(sqrtf(ss), 1e-12f);
        ushort4 o;
        o.x = f2bf(v.x * inv);
        o.y = f2bf(v.y * inv);
        o.z = f2bf(v.z * inv);
        o.w = f2bf(v.w * inv);
        ((ushort4*)(zn + (size_t)k * (B_N * F_D) + (size_t)b * F_D))[lane] = o;
        *(ushort4*)(&Zs[(w * 8 + k) * LSTR + lane * 4]) = o;
    }
    __syncthreads();

    // pos: wave 0 -> local samples 0,1 ; wave 1 -> local samples 2,3
    if (w < 2) {
        int q = lane >> 4, li = lane & 15;
        int lr = (w * 2 + (li >> 3)) * 8 + (li & 7);  // local row: sample*8 + view
        short8 a[8];
        #pragma unroll
        for (int kk = 0; kk < 8; kk++)
            a[kk] = *(const short8*)(&Zs[lr * LSTR + kk * 32 + q * 8]);
        floatx4 acc = {0.f, 0.f, 0.f, 0.f};
        #pragma unroll
        for (int kk = 0; kk < 8; kk++)
            acc = __builtin_amdgcn_mfma_f32_16x16x32_bf16(a[kk], a[kk], acc, 0, 0, 0);
        float p0 = 0.f, p1 = 0.f;
        #pragma unroll
        for (int r = 0; r < 4; r++) {
            int row = q * 4 + r, col = li;
            bool same_sample = (row >> 3) == (col >> 3);
            if (same_sample && row != col) {
                float e = EXP2F(acc[r]);   // acc already = 2*log2e*dot
                if (row < 8) p0 += e; else p1 += e;
            }
        }
        p0 = wave_reduce_sum(p0);
        p1 = wave_reduce_sum(p1);
        if (lane == 0) {
            int s0 = blockIdx.x * 4 + w * 2;
            pos[s0] = p0;
            pos[s0 + 1] = p1;
        }
    }
}

// One ct-sweep over the 64 staged B-columns currently in Bs.
// Uses: a, rs, cs, diag, r0, q, li; C0 = global col base, CSB = cs index base.
#define CT_SWEEP(C0, CSB)                                                        \
    do {                                                                         \
        _Pragma("unroll")                                                        \
        for (int ct = 0; ct < 4; ++ct) {                                         \
            const unsigned short* bp = &Bs[(ct * 16 + li) * LSTR + q * 8];       \
            floatx4 acc[2];                                                      \
            acc[0] = (floatx4){0.f, 0.f, 0.f, 0.f};                              \
            acc[1] = (floatx4){0.f, 0.f, 0.f, 0.f};                              \
            _Pragma("unroll")                                                    \
            for (int kk = 0; kk < 8; kk++) {                                     \
                short8 bf = *(const short8*)(bp + kk * 32);                      \
                acc[0] = __builtin_amdgcn_mfma_f32_16x16x32_bf16(a[0][kk], bf, acc[0], 0, 0, 0); \
                acc[1] = __builtin_amdgcn_mfma_f32_16x16x32_bf16(a[1][kk], bf, acc[1], 0, 0, 0); \
            }                                                                    \
            int gcol = (C0) + ct * 16 + li;                                      \
            float csum = 0.f;                                                    \
            _Pragma("unroll")                                                    \
            for (int s = 0; s < 2; s++) {                                        \
                _Pragma("unroll")                                                \
                for (int r = 0; r < 4; r++) {                                    \
                    float e = EXP2F(acc[s][r]);                                  \
                    if (diag) {                                                  \
                        int grow = r0 + s * 16 + q * 4 + r;                      \
                        if (grow == gcol) e = 0.f;                               \
                    }                                                            \
                    rs[s][r] += e;                                               \
                    csum += e;                                                   \
                }                                                                \
            }                                                                    \
            cs[(CSB) + ct] = csum;                                               \
        }                                                                        \
    } while (0)

// ---------------------------------------------------------------------------
// Kernel 2 (symmetric-halved): per view d, upper-triangle 128x128 tiles of
// S = exp(2 * Z Z^T): row-sums -> ns8[d][i*128+..]; off-diag tiles also
// col-sums -> ns8[d][j*128+..] (mirrored tile).
// R6 spill-free structure (VGPR 76 -> ~140 here): 256 threads (4 waves),
// each wave owns 32 A-rows; B staged in LDS 64 cols at a time.
// NEW (T14 async-STAGE split): BOTH stages' B-loads are issued up front into
// registers; stage-1's ds_write happens after the stage-0 compute barrier,
// so its ~900-cycle global latency hides under stage-0 MFMA+exp. One exposed
// global latency per block instead of two; 3 barriers instead of 4.
// ---------------------------------------------------------------------------
__global__ __launch_bounds__(256, 2)
void neg_kernel(const unsigned short* __restrict__ zn,
                float* __restrict__ ns8) {
    __shared__ __align__(16) unsigned short Bs[BC * LSTR];  // 33 KB
    const int bid = blockIdx.x;
    const int d = bid & 7;            // view == XCD (perf heuristic; FETCH 10.4
                                      // vs 38.7 MB measured, R1 vs R2)
    int trem = bid >> 3;              // 0..135 -> (i,j), i<=j
    int i = 0;
    while (trem >= 16 - i) { trem -= 16 - i; ++i; }
    const int j = i + trem;
    const bool diag = (i == j);
    const unsigned short* Z = zn + (size_t)d * (B_N * F_D);
    int tid = threadIdx.x, w = tid >> 6, lane = tid & 63;
    int q = lane >> 4, li = lane & 15;
    int r0 = i * TILE + w * 32;       // this wave's 32 A-rows

    // A-frags: issued first, 64 VGPR resident whole kernel
    short8 a[2][8];
    #pragma unroll
    for (int s = 0; s < 2; s++)
        #pragma unroll
        for (int kk = 0; kk < 8; kk++)
            a[s][kk] = *(const short8*)(Z + (size_t)(r0 + s * 16 + li) * F_D + kk * 32 + q * 8);

    // B staging addressing: thread covers 8 chunks; chunk it -> (row, kc)
    int brow = 0, bkc = 0;  // computed per-it below
    short8 breg[8];
    // stage-0 loads (in flight with A-loads)
    #pragma unroll
    for (int it = 0; it < 8; ++it) {
        int idx = it * 256 + tid;
        int row = idx >> 5, kc = idx & 31;
        breg[it] = *(const short8*)(Z + (size_t)(j * TILE + row) * F_D + kc * 8);
    }
    // write stage-0 to LDS (waits on stage-0 vmcnt: the one exposed latency)
    #pragma unroll
    for (int it = 0; it < 8; ++it) {
        int idx = it * 256 + tid;
        int row = idx >> 5, kc = idx & 31;
        *(short8*)(&Bs[row * LSTR + kc * 8]) = breg[it];
    }
    // stage-1 loads: issue NOW; they arrive during stage-0 compute
    #pragma unroll
    for (int it = 0; it < 8; ++it) {
        int idx = it * 256 + tid;
        int row = idx >> 5, kc = idx & 31;
        breg[it] = *(const short8*)(Z + (size_t)(j * TILE + BC + row) * F_D + kc * 8);
    }

    float rs[2][4];
    #pragma unroll
    for (int s = 0; s < 2; s++)
        #pragma unroll
        for (int r = 0; r < 4; r++) rs[s][r] = 0.f;
    float cs[8];

    __syncthreads();
    CT_SWEEP(j * TILE, 0);            // stage-0 compute (B1 loads in flight)
    __syncthreads();
    // stage-1 ds_write (breg long since arrived)
    #pragma unroll
    for (int it = 0; it < 8; ++it) {
        int idx = it * 256 + tid;
        int row = idx >> 5, kc = idx & 31;
        *(short8*)(&Bs[row * LSTR + kc * 8]) = breg[it];
    }
    __syncthreads();
    CT_SWEEP(j * TILE + BC, 4);       // stage-1 compute

    // row sums: reduce across the 16 column-lanes; lanes li<8 each own one
    // (s,r) value and issue one atomic
    #pragma unroll
    for (int off = 1; off < 16; off <<= 1)
        #pragma unroll
        for (int s = 0; s < 2; s++)
            #pragma unroll
            for (int r = 0; r < 4; r++)
                rs[s][r] += __shfl_xor(rs[s][r], off, 64);
    {
        float rv = 0.f;
        #pragma unroll
        for (int s = 0; s < 2; s++)
            #pragma unroll
            for (int r = 0; r < 4; r++)
                if (li == s * 4 + r) rv = rs[s][r];
        if (li < 8)
            atomicAdd(&ns8[d * B_N + r0 + (li >> 2) * 16 + q * 4 + (li & 3)], rv);
    }

    // col sums (mirrored tile coverage): cross-q reduce; each wave atomics its
    // own 32-row contribution (4 waves -> 4 atomics/column, negligible)
    if (!diag) {
        #pragma unroll
        for (int c = 0; c < 8; c++) {
            cs[c] += __shfl_xor(cs[c], 16, 64);
            cs[c] += __shfl_xor(cs[c], 32, 64);
        }
        float v0 = 0.f, v1 = 0.f;
        #pragma unroll
        for (int c = 0; c < 4; c++)
            if (q == c) { v0 = cs[c]; v1 = cs[c + 4]; }
        atomicAdd(&ns8[d * B_N + j * TILE + q * 16 + li], v0);
        atomicAdd(&ns8[d * B_N + j * TILE + 64 + q * 16 + li], v1);
    }
}

// ---------------------------------------------------------------------------
// Kernel 3: neg[b] = sum_d ns8[d][b] / (B-1); logits = pos/(pos+neg);
// loss = max + log(sum exp(l-max)) - mean(l)
// ---------------------------------------------------------------------------
__global__ void final_kernel(const float* __restrict__ pos,
                             const float* __restrict__ ns8,
                             float* __restrict__ out) {
    __shared__ float red[256];
    int t = threadIdx.x;
    float vals[8];
    float lmax = -1e30f;
    #pragma unroll
    for (int i = 0; i < 8; i++) {
        int idx = t * 8 + i;
        float nsum = 0.f;
        #pragma unroll
        for (int d = 0; d < D_V; d++) nsum += ns8[d * B_N + idx];
        float p = pos[idx];
        float n = nsum * (1.0f / (float)(B_N - 1));
        float l = p / (p + n);
        vals[i] = l;
        lmax = fmaxf(lmax, l);
    }
    red[t] = lmax; __syncthreads();
    for (int s = 128; s > 0; s >>= 1) {
        if (t < s) red[t] = fmaxf(red[t], red[t + s]);
        __syncthreads();
    }
    float m = red[0]; __syncthreads();
    float se = 0.f, sl = 0.f;
    #pragma unroll
    for (int i = 0; i < 8; i++) { se += expf(vals[i] - m); sl += vals[i]; }
    red[t] = se; __syncthreads();
    for (int s = 128; s > 0; s >>= 1) {
        if (t < s) red[t] += red[t + s];
        __syncthreads();
    }
    float S = red[0]; __syncthreads();
    red[t] = sl; __syncthreads();
    for (int s = 128; s > 0; s >>= 1) {
        if (t < s) red[t] += red[t + s];
        __syncthreads();
    }
    if (t == 0) out[0] = m + logf(S) - red[0] / (float)B_N;
}

extern "C" void kernel_launch(void* const* d_in, const int* in_sizes, int n_in,
                              void* d_out, int out_size, void* d_ws, size_t ws_size,
                              hipStream_t stream) {
    const float* z = (const float*)d_in[0];
    float* out = (float*)d_out;
    unsigned short* zn = (unsigned short*)d_ws;                        // 8 MB bf16 (pre-scaled)
    float* ns8 = (float*)((char*)d_ws + (size_t)D_V * B_N * F_D * 2);  // 64 KB
    float* pos = ns8 + D_V * B_N;                                      // 8 KB

    np_kernel<<<dim3(512), 256, 0, stream>>>(z, zn, ns8, pos);
    neg_kernel<<<dim3(136 * 8), 256, 0, stream>>>(zn, ns8);
    final_kernel<<<1, 256, 0, stream>>>(pos, ns8, out);
}